// Round 3
// baseline (1166.747 us; speedup 1.0000x reference)
//
#include <hip/hip_runtime.h>

#define DIN 128
#define HID 128
#define BB  32
#define NN  2048
#define LOG2E 1.44269504088896340736f

typedef float  f32x4   __attribute__((ext_vector_type(4)));
typedef __bf16 bf16x4v __attribute__((ext_vector_type(4)));
typedef __bf16 bf16x8  __attribute__((ext_vector_type(8)));

__device__ __forceinline__ float tanh_fast(float x) {
  float e = __expf(2.0f * x);
  return 1.0f - 2.0f / (e + 1.0f);
}

// ---------------------------------------------------------------------------
// Kernel 0: W[d][h] (fp32) -> wt[h][d] (bf16), for q,k,v. 3 blocks x 256.
// ---------------------------------------------------------------------------
__global__ __launch_bounds__(256) void wt_kernel(
    const float* __restrict__ Wq, const float* __restrict__ Wk,
    const float* __restrict__ Wv, __bf16* __restrict__ wt) {
  const float* W = (blockIdx.x == 0) ? Wq : (blockIdx.x == 1) ? Wk : Wv;
  __bf16* dst = wt + blockIdx.x * (DIN * HID);
  int t = threadIdx.x;
#pragma unroll
  for (int c = 0; c < 16; ++c) {
    int o = c * 1024 + t * 4;
    int d = o >> 7, h = o & 127;
    f32x4 v = *(const f32x4*)(W + d * HID + h);
    dst[(h + 0) * DIN + d] = (__bf16)v.x;
    dst[(h + 1) * DIN + d] = (__bf16)v.y;
    dst[(h + 2) * DIN + d] = (__bf16)v.z;
    dst[(h + 3) * DIN + d] = (__bf16)v.w;
  }
}

// ---------------------------------------------------------------------------
// Kernel A: q = tanh(xWq+bq)*LOG2E, k = tanh(xWk+bk) row-major bf16 [B*N][H];
//           vt = tanh(xWv+bv)^T per batch, bf16 [B][H][N].
// ---------------------------------------------------------------------------
__global__ __launch_bounds__(256) void proj_kernel(
    const float* __restrict__ x, const __bf16* __restrict__ wt,
    const float* __restrict__ bq, const float* __restrict__ bk,
    const float* __restrict__ bv, __bf16* __restrict__ qbf,
    __bf16* __restrict__ kbf, __bf16* __restrict__ vtbf) {
  int tid = threadIdx.x;
  int lane = tid & 63, w = tid >> 6;
  int l15 = lane & 15, quad = lane >> 4;
  long i0 = (long)blockIdx.x * 64;

  bf16x8 bx[4][4];
#pragma unroll
  for (int nt = 0; nt < 4; ++nt) {
    const float* xp = x + (i0 + nt * 16 + l15) * DIN;
#pragma unroll
    for (int ks = 0; ks < 4; ++ks) {
      int d0 = ks * 32 + quad * 8;
      f32x4 a = *(const f32x4*)(xp + d0);
      f32x4 b = *(const f32x4*)(xp + d0 + 4);
      bf16x8 f;
      f[0] = (__bf16)a.x; f[1] = (__bf16)a.y; f[2] = (__bf16)a.z; f[3] = (__bf16)a.w;
      f[4] = (__bf16)b.x; f[5] = (__bf16)b.y; f[6] = (__bf16)b.z; f[7] = (__bf16)b.w;
      bx[nt][ks] = f;
    }
  }

#pragma unroll
  for (int p = 0; p < 2; ++p) {
    const __bf16* wtp = wt + p * DIN * HID;
    const float* bias = (p == 0) ? bq : bk;
    __bf16* outp = (p == 0) ? qbf : kbf;
#pragma unroll
    for (int nt = 0; nt < 8; ++nt) {
      int h0 = nt * 16 + l15;
      f32x4 acc = {0.f, 0.f, 0.f, 0.f};
#pragma unroll
      for (int ks = 0; ks < 4; ++ks) {
        bf16x8 wf = *(const bf16x8*)(wtp + (long)h0 * DIN + ks * 32 + quad * 8);
        acc = __builtin_amdgcn_mfma_f32_16x16x32_bf16(bx[w][ks], wf, acc, 0, 0, 0);
      }
      float bcol = bias[h0];
      long rowb = i0 + w * 16 + quad * 4;
#pragma unroll
      for (int r = 0; r < 4; ++r) {
        float val = tanh_fast(acc[r] + bcol);
        if (p == 0) val *= LOG2E;
        outp[(rowb + r) * HID + h0] = (__bf16)val;
      }
    }
  }

  {
    const __bf16* wtp = wt + 2 * DIN * HID;
    long bb = i0 >> 11;
    int nloc = (int)(i0 & 2047);
    long vbase = bb * (long)HID * NN;
#pragma unroll
    for (int s = 0; s < 2; ++s) {
      int hb = w * 32 + s * 16;
      bf16x8 af[4];
#pragma unroll
      for (int ks = 0; ks < 4; ++ks)
        af[ks] = *(const bf16x8*)(wtp + (long)(hb + l15) * DIN + ks * 32 + quad * 8);
      float bvr[4];
#pragma unroll
      for (int r = 0; r < 4; ++r) bvr[r] = bv[hb + quad * 4 + r];
#pragma unroll
      for (int nt = 0; nt < 4; ++nt) {
        f32x4 acc = {0.f, 0.f, 0.f, 0.f};
#pragma unroll
        for (int ks = 0; ks < 4; ++ks)
          acc = __builtin_amdgcn_mfma_f32_16x16x32_bf16(af[ks], bx[nt][ks], acc, 0, 0, 0);
        int hrow = hb + quad * 4;
        int ncol = nloc + nt * 16 + l15;
#pragma unroll
        for (int r = 0; r < 4; ++r) {
          float val = tanh_fast(acc[r] + bvr[r]);
          vtbf[vbase + (long)(hrow + r) * NN + ncol] = (__bf16)val;
        }
      }
    }
  }
}

// ---------------------------------------------------------------------------
// Kernel B: barrier-free flash attention.
// grid = 512 blocks x 256 threads (4 waves). Block owns 128 q-rows; wave owns
// 32 (two 16-row groups qg). K and V fragments are loaded DIRECTLY from
// global in MFMA layout (L1/L2-served: K+V per batch = 1 MB). Mask streamed
// with nontemporal loads. No __syncthreads anywhere; only LDS use is the
// wave-private P layout round-trip.
// ---------------------------------------------------------------------------
#define PSTR 72    // P row stride: 144 B, 16B-aligned

__global__ __launch_bounds__(256) void attn_kernel(
    const __bf16* __restrict__ qbf, const __bf16* __restrict__ kbf,
    const __bf16* __restrict__ vtbf, const float* __restrict__ mask,
    float* __restrict__ out) {
  __shared__ __bf16 Pl[4 * 32 * PSTR];   // 18432 B

  const int tid = threadIdx.x;
  const int lane = tid & 63, w = tid >> 6;
  const int l15 = lane & 15, quad = lane >> 4;
  // XCD swizzle: 64 consecutive virtual blocks (= 4 whole batches) per XCD
  const int bid = blockIdx.x;
  const int vb = (bid >> 3) | ((bid & 7) << 6);
  const int b = vb >> 4;
  const int i0 = (vb & 15) * 128;
  const long kvbase = (long)b * NN * HID;

  // Q fragments (B operand of S^T): lane l15 = q-row, quad*8+e = d
  bf16x8 qf[2][4];
#pragma unroll
  for (int qg = 0; qg < 2; ++qg) {
    const __bf16* qp =
        qbf + kvbase + (long)(i0 + w * 32 + qg * 16 + l15) * HID + quad * 8;
#pragma unroll
    for (int ks = 0; ks < 4; ++ks) qf[qg][ks] = *(const bf16x8*)(qp + ks * 32);
  }

  // global fragment base pointers
  const __bf16* kgl = kbf + kvbase + (long)l15 * HID + quad * 8;
  const __bf16* vgl = vtbf + (long)b * HID * NN + (long)l15 * NN + quad * 8;
  const float* mpl[2];
#pragma unroll
  for (int qg = 0; qg < 2; ++qg)
    mpl[qg] = mask + ((long)b * NN + (i0 + w * 32 + qg * 16 + l15)) * NN + quad * 4;
  __bf16* Pw = Pl + w * 32 * PSTR;

  f32x4 O[2][8];
#pragma unroll
  for (int qg = 0; qg < 2; ++qg)
#pragma unroll
    for (int nt = 0; nt < 8; ++nt) O[qg][nt] = (f32x4){0.f, 0.f, 0.f, 0.f};
  float mrow[2] = {-1e30f, -1e30f}, lrow[2] = {0.0f, 0.0f};

#pragma unroll 1
  for (int jt = 0; jt < 32; ++jt) {
    const int j0 = jt * 64;

    // ---- mask tile (nontemporal: don't evict K/V from L1) -> bitmasks
    unsigned mbits[2];
#pragma unroll
    for (int qg = 0; qg < 2; ++qg) {
      f32x4 mr[4];
#pragma unroll
      for (int t = 0; t < 4; ++t)
        mr[t] = __builtin_nontemporal_load((const f32x4*)(mpl[qg] + j0 + t * 16));
      float mb = 0.f;
#pragma unroll
      for (int t = 0; t < 4; ++t)
#pragma unroll
        for (int r = 0; r < 4; ++r)
          mb = fmaf(mr[t][r], (float)(1u << (t * 4 + r)), mb);  // mask is 0/1
      mbits[qg] = (unsigned)mb;
    }

    // ---- S^T = K Q^T : rows = keys (t*16 + quad*4+r), cols = q (l15)
    f32x4 S[2][4];
#pragma unroll
    for (int t = 0; t < 4; ++t) {
      const __bf16* kp = kgl + (long)(j0 + t * 16) * HID;
      f32x4 a0 = {0.f, 0.f, 0.f, 0.f}, a1 = {0.f, 0.f, 0.f, 0.f};
#pragma unroll
      for (int ks = 0; ks < 4; ++ks) {
        bf16x8 kf = *(const bf16x8*)(kp + ks * 32);
        a0 = __builtin_amdgcn_mfma_f32_16x16x32_bf16(kf, qf[0][ks], a0, 0, 0, 0);
        a1 = __builtin_amdgcn_mfma_f32_16x16x32_bf16(kf, qf[1][ks], a1, 0, 0, 0);
      }
      S[0][t] = a0;
      S[1][t] = a1;
    }

    // ---- masked online softmax (log2 domain), P store to wave-private LDS
#pragma unroll
    for (int qg = 0; qg < 2; ++qg) {
      float tmx = -1e30f;
#pragma unroll
      for (int t = 0; t < 4; ++t)
#pragma unroll
        for (int r = 0; r < 4; ++r) {
          float s = ((mbits[qg] >> (t * 4 + r)) & 1u) ? S[qg][t][r] : -1e30f;
          S[qg][t][r] = s;
          tmx = fmaxf(tmx, s);
        }
      tmx = fmaxf(tmx, __shfl_xor(tmx, 16));
      tmx = fmaxf(tmx, __shfl_xor(tmx, 32));
      const float mnew = fmaxf(mrow[qg], tmx);
      const float alpha = exp2f(mrow[qg] - mnew);
      float rs = 0.0f;
#pragma unroll
      for (int t = 0; t < 4; ++t) {
        bf16x4v pb;
#pragma unroll
        for (int r = 0; r < 4; ++r) {
          float p = exp2f(S[qg][t][r] - mnew);
          rs += p;
          pb[r] = (__bf16)p;
        }
        *(bf16x4v*)(Pw + (qg * 16 + l15) * PSTR + t * 16 + quad * 4) = pb;
      }
      rs += __shfl_xor(rs, 16);
      rs += __shfl_xor(rs, 32);
      lrow[qg] = lrow[qg] * alpha + rs;
      mrow[qg] = mnew;
      // rescale O (O rows are quad*4+r; alpha lives at lane l15 = q-row)
      float ar[4];
#pragma unroll
      for (int r = 0; r < 4; ++r) ar[r] = __shfl(alpha, (quad << 2) + r);
#pragma unroll
      for (int nt = 0; nt < 8; ++nt)
#pragma unroll
        for (int r = 0; r < 4; ++r) O[qg][nt][r] *= ar[r];
    }

    // ---- P: LDS -> A-layout fragments (wave-private, no barrier)
    bf16x8 pf[2][2];
#pragma unroll
    for (int qg = 0; qg < 2; ++qg)
#pragma unroll
      for (int js = 0; js < 2; ++js)
        pf[qg][js] =
            *(const bf16x8*)(Pw + (qg * 16 + l15) * PSTR + js * 32 + quad * 8);

    // ---- O += P V  (V fragments direct from global, L1/L2-served)
#pragma unroll
    for (int nt = 0; nt < 8; ++nt) {
      const __bf16* vp = vgl + (long)(nt * 16) * NN + j0;
#pragma unroll
      for (int js = 0; js < 2; ++js) {
        bf16x8 vf = *(const bf16x8*)(vp + js * 32);
        O[0][nt] = __builtin_amdgcn_mfma_f32_16x16x32_bf16(pf[0][js], vf, O[0][nt], 0, 0, 0);
        O[1][nt] = __builtin_amdgcn_mfma_f32_16x16x32_bf16(pf[1][js], vf, O[1][nt], 0, 0, 0);
      }
    }
  }

  // ---- epilogue: out[i][h] = O / l
#pragma unroll
  for (int qg = 0; qg < 2; ++qg) {
    const float inv = 1.0f / lrow[qg];
    float il[4];
#pragma unroll
    for (int r = 0; r < 4; ++r) il[r] = __shfl(inv, (quad << 2) + r);
    const long rowb = (long)b * NN + i0 + w * 32 + qg * 16 + quad * 4;
#pragma unroll
    for (int r = 0; r < 4; ++r) {
      float* op = out + (rowb + r) * HID;
#pragma unroll
      for (int nt = 0; nt < 8; ++nt) op[nt * 16 + l15] = O[qg][nt][r] * il[r];
    }
  }
}

// ---------------------------------------------------------------------------
extern "C" void kernel_launch(void* const* d_in, const int* in_sizes, int n_in,
                              void* d_out, int out_size, void* d_ws, size_t ws_size,
                              hipStream_t stream) {
  const float* x    = (const float*)d_in[0];
  const float* mask = (const float*)d_in[1];
  const float* Wv   = (const float*)d_in[2];
  const float* bv   = (const float*)d_in[3];
  const float* Wk   = (const float*)d_in[4];
  const float* bk   = (const float*)d_in[5];
  const float* Wq   = (const float*)d_in[6];
  const float* bq   = (const float*)d_in[7];
  float* out = (float*)d_out;

  __bf16* ws = (__bf16*)d_ws;
  __bf16* wt   = ws;                      // 3 * 128*128
  __bf16* qbf  = ws + 3 * DIN * HID;      // B*N*H
  __bf16* kbf  = qbf + (long)BB * NN * HID;
  __bf16* vtbf = kbf + (long)BB * NN * HID;

  wt_kernel<<<3, 256, 0, stream>>>(Wq, Wk, Wv, wt);
  proj_kernel<<<BB * NN / 64, 256, 0, stream>>>(x, wt, bq, bk, bv, qbf, kbf, vtbf);
  attn_kernel<<<512, 256, 0, stream>>>(qbf, kbf, vtbf, mask, out);
}

// Round 4
// 863.997 us; speedup vs baseline: 1.3504x; 1.3504x over previous
//
#include <hip/hip_runtime.h>

#define DIN 128
#define HID 128
#define BB  32
#define NN  2048
#define LOG2E 1.44269504088896340736f

typedef float  f32x4   __attribute__((ext_vector_type(4)));
typedef __bf16 bf16x4v __attribute__((ext_vector_type(4)));
typedef __bf16 bf16x8  __attribute__((ext_vector_type(8)));

__device__ __forceinline__ float tanh_fast(float x) {
  float e = __expf(2.0f * x);
  return 1.0f - 2.0f / (e + 1.0f);
}

// ---------------------------------------------------------------------------
// Kernel 0: W[d][h] (fp32) -> wt[h][d] (bf16), for q,k,v. 3 blocks x 256.
// ---------------------------------------------------------------------------
__global__ __launch_bounds__(256) void wt_kernel(
    const float* __restrict__ Wq, const float* __restrict__ Wk,
    const float* __restrict__ Wv, __bf16* __restrict__ wt) {
  const float* W = (blockIdx.x == 0) ? Wq : (blockIdx.x == 1) ? Wk : Wv;
  __bf16* dst = wt + blockIdx.x * (DIN * HID);
  int t = threadIdx.x;
#pragma unroll
  for (int c = 0; c < 16; ++c) {
    int o = c * 1024 + t * 4;
    int d = o >> 7, h = o & 127;
    f32x4 v = *(const f32x4*)(W + d * HID + h);
    dst[(h + 0) * DIN + d] = (__bf16)v.x;
    dst[(h + 1) * DIN + d] = (__bf16)v.y;
    dst[(h + 2) * DIN + d] = (__bf16)v.z;
    dst[(h + 3) * DIN + d] = (__bf16)v.w;
  }
}

// ---------------------------------------------------------------------------
// Kernel A: q = tanh(xWq+bq)*LOG2E, k = tanh(xWk+bk) row-major bf16 [B*N][H];
//           vt = tanh(xWv+bv)^T per batch, bf16 [B][H][N].
// ---------------------------------------------------------------------------
__global__ __launch_bounds__(256) void proj_kernel(
    const float* __restrict__ x, const __bf16* __restrict__ wt,
    const float* __restrict__ bq, const float* __restrict__ bk,
    const float* __restrict__ bv, __bf16* __restrict__ qbf,
    __bf16* __restrict__ kbf, __bf16* __restrict__ vtbf) {
  int tid = threadIdx.x;
  int lane = tid & 63, w = tid >> 6;
  int l15 = lane & 15, quad = lane >> 4;
  long i0 = (long)blockIdx.x * 64;

  bf16x8 bx[4][4];
#pragma unroll
  for (int nt = 0; nt < 4; ++nt) {
    const float* xp = x + (i0 + nt * 16 + l15) * DIN;
#pragma unroll
    for (int ks = 0; ks < 4; ++ks) {
      int d0 = ks * 32 + quad * 8;
      f32x4 a = *(const f32x4*)(xp + d0);
      f32x4 b = *(const f32x4*)(xp + d0 + 4);
      bf16x8 f;
      f[0] = (__bf16)a.x; f[1] = (__bf16)a.y; f[2] = (__bf16)a.z; f[3] = (__bf16)a.w;
      f[4] = (__bf16)b.x; f[5] = (__bf16)b.y; f[6] = (__bf16)b.z; f[7] = (__bf16)b.w;
      bx[nt][ks] = f;
    }
  }

#pragma unroll
  for (int p = 0; p < 2; ++p) {
    const __bf16* wtp = wt + p * DIN * HID;
    const float* bias = (p == 0) ? bq : bk;
    __bf16* outp = (p == 0) ? qbf : kbf;
#pragma unroll
    for (int nt = 0; nt < 8; ++nt) {
      int h0 = nt * 16 + l15;
      f32x4 acc = {0.f, 0.f, 0.f, 0.f};
#pragma unroll
      for (int ks = 0; ks < 4; ++ks) {
        bf16x8 wf = *(const bf16x8*)(wtp + (long)h0 * DIN + ks * 32 + quad * 8);
        acc = __builtin_amdgcn_mfma_f32_16x16x32_bf16(bx[w][ks], wf, acc, 0, 0, 0);
      }
      float bcol = bias[h0];
      long rowb = i0 + w * 16 + quad * 4;
#pragma unroll
      for (int r = 0; r < 4; ++r) {
        float val = tanh_fast(acc[r] + bcol);
        if (p == 0) val *= LOG2E;
        outp[(rowb + r) * HID + h0] = (__bf16)val;
      }
    }
  }

  {
    const __bf16* wtp = wt + 2 * DIN * HID;
    long bb = i0 >> 11;
    int nloc = (int)(i0 & 2047);
    long vbase = bb * (long)HID * NN;
#pragma unroll
    for (int s = 0; s < 2; ++s) {
      int hb = w * 32 + s * 16;
      bf16x8 af[4];
#pragma unroll
      for (int ks = 0; ks < 4; ++ks)
        af[ks] = *(const bf16x8*)(wtp + (long)(hb + l15) * DIN + ks * 32 + quad * 8);
      float bvr[4];
#pragma unroll
      for (int r = 0; r < 4; ++r) bvr[r] = bv[hb + quad * 4 + r];
#pragma unroll
      for (int nt = 0; nt < 4; ++nt) {
        f32x4 acc = {0.f, 0.f, 0.f, 0.f};
#pragma unroll
        for (int ks = 0; ks < 4; ++ks)
          acc = __builtin_amdgcn_mfma_f32_16x16x32_bf16(af[ks], bx[nt][ks], acc, 0, 0, 0);
        int hrow = hb + quad * 4;
        int ncol = nloc + nt * 16 + l15;
#pragma unroll
        for (int r = 0; r < 4; ++r) {
          float val = tanh_fast(acc[r] + bvr[r]);
          vtbf[vbase + (long)(hrow + r) * NN + ncol] = (__bf16)val;
        }
      }
    }
  }
}

// ---------------------------------------------------------------------------
// Kernel B: flash attention, LDS-staged + register-prefetch pipeline.
// grid = 512 blocks x 256 threads (4 waves). Block owns 128 q-rows; wave owns
// 32 (two 16-row groups qg) so every K/V LDS fragment read feeds TWO MFMAs
// (halves LDS read traffic per q-row vs R2). K/V/mask for tile j+1 are
// register-prefetched during compute of tile j, staged to LDS after barrier.
// 2 blocks/CU (LDS 54.3 KB).
// ---------------------------------------------------------------------------
#define KSTR 136   // Ks row stride: 272 B, 16B-aligned, bank-optimal
#define VSTR 72    // Vts row stride: 144 B, 16B-aligned, bank-optimal
#define PSTR 72    // P row stride

__global__ __launch_bounds__(256, 2) void attn_kernel(
    const __bf16* __restrict__ qbf, const __bf16* __restrict__ kbf,
    const __bf16* __restrict__ vtbf, const float* __restrict__ mask,
    float* __restrict__ out) {
  __shared__ __bf16 Ks[64 * KSTR];       // 17408 B
  __shared__ __bf16 Vts[128 * VSTR];     // 18432 B
  __shared__ __bf16 Pl[4 * 32 * PSTR];   // 18432 B  (total 54272 B)

  const int tid = threadIdx.x;
  const int lane = tid & 63, w = tid >> 6;
  const int l15 = lane & 15, quad = lane >> 4;
  // XCD swizzle: 64 consecutive virtual blocks (= 4 whole batches) per XCD
  const int bid = blockIdx.x;
  const int vb = (bid >> 3) | ((bid & 7) << 6);
  const int b = vb >> 4;
  const int i0 = (vb & 15) * 128;
  const long kvbase = (long)b * NN * HID;

  // Q fragments (B operand of S^T): lane l15 = q-row, quad*8+e = d
  bf16x8 qf[2][4];
#pragma unroll
  for (int qg = 0; qg < 2; ++qg) {
    const __bf16* qp =
        qbf + kvbase + (long)(i0 + w * 32 + qg * 16 + l15) * HID + quad * 8;
#pragma unroll
    for (int ks = 0; ks < 4; ++ks) qf[qg][ks] = *(const bf16x8*)(qp + ks * 32);
  }

  // staging geometry (256 threads, 4 passes each for K and Vt)
  const int krow = tid >> 4, kcol = (tid & 15) * 8;   // +16 rows per pass
  const int vrow = tid >> 3, vcol = (tid & 7) * 8;    // +32 rows per pass
  const __bf16* kg = kbf + kvbase + (long)krow * HID + kcol;
  const __bf16* vg = vtbf + (long)b * HID * NN + (long)vrow * NN + vcol;
  __bf16* ksd = Ks + krow * KSTR + kcol;
  __bf16* vsd = Vts + vrow * VSTR + vcol;
  const float* mpl[2];
#pragma unroll
  for (int qg = 0; qg < 2; ++qg)
    mpl[qg] = mask + ((long)b * NN + (i0 + w * 32 + qg * 16 + l15)) * NN + quad * 4;
  __bf16* Pw = Pl + w * 32 * PSTR;

  f32x4 O[2][8];
#pragma unroll
  for (int qg = 0; qg < 2; ++qg)
#pragma unroll
    for (int nt = 0; nt < 8; ++nt) O[qg][nt] = (f32x4){0.f, 0.f, 0.f, 0.f};
  float mrow[2] = {-1e30f, -1e30f}, lrow[2] = {0.0f, 0.0f};

  // ---- prologue: load + stage tile 0
  bf16x8 kr[4], vr[4];
  f32x4 mr[2][4];
#pragma unroll
  for (int p = 0; p < 4; ++p) {
    kr[p] = *(const bf16x8*)(kg + (long)p * 16 * HID);
    vr[p] = *(const bf16x8*)(vg + (long)p * 32 * NN);
  }
#pragma unroll
  for (int qg = 0; qg < 2; ++qg)
#pragma unroll
    for (int t = 0; t < 4; ++t)
      mr[qg][t] = __builtin_nontemporal_load((const f32x4*)(mpl[qg] + t * 16));
#pragma unroll
  for (int p = 0; p < 4; ++p) {
    *(bf16x8*)(ksd + p * 16 * KSTR) = kr[p];
    *(bf16x8*)(vsd + p * 32 * VSTR) = vr[p];
  }
  unsigned mbits[2];
#pragma unroll
  for (int qg = 0; qg < 2; ++qg) {
    float mb = 0.f;
#pragma unroll
    for (int t = 0; t < 4; ++t)
#pragma unroll
      for (int r = 0; r < 4; ++r)
        mb = fmaf(mr[qg][t][r], (float)(1u << (t * 4 + r)), mb);  // mask is 0/1
    mbits[qg] = (unsigned)mb;
  }
  __syncthreads();

#pragma unroll 1
  for (int jt = 0; jt < 32; ++jt) {
    const int jn = (jt < 31) ? jt + 1 : 31;   // redundant reload on last iter
    // ---- issue prefetch for tile jn (in flight across the compute phase)
    {
      const __bf16* kgn = kg + (long)jn * 64 * HID;
      const __bf16* vgn = vg + jn * 64;
#pragma unroll
      for (int p = 0; p < 4; ++p) {
        kr[p] = *(const bf16x8*)(kgn + (long)p * 16 * HID);
        vr[p] = *(const bf16x8*)(vgn + (long)p * 32 * NN);
      }
#pragma unroll
      for (int qg = 0; qg < 2; ++qg)
#pragma unroll
        for (int t = 0; t < 4; ++t)
          mr[qg][t] = __builtin_nontemporal_load(
              (const f32x4*)(mpl[qg] + jn * 64 + t * 16));
    }

    // ---- S^T = K Q^T : rows = keys (t*16+quad*4+r), cols = q (l15)
    f32x4 S[2][4];
#pragma unroll
    for (int t = 0; t < 4; ++t) {
      const __bf16* kp = Ks + (t * 16 + l15) * KSTR + quad * 8;
      f32x4 a0 = {0.f, 0.f, 0.f, 0.f}, a1 = {0.f, 0.f, 0.f, 0.f};
#pragma unroll
      for (int ks = 0; ks < 4; ++ks) {
        bf16x8 kf = *(const bf16x8*)(kp + ks * 32);
        a0 = __builtin_amdgcn_mfma_f32_16x16x32_bf16(kf, qf[0][ks], a0, 0, 0, 0);
        a1 = __builtin_amdgcn_mfma_f32_16x16x32_bf16(kf, qf[1][ks], a1, 0, 0, 0);
      }
      S[0][t] = a0;
      S[1][t] = a1;
    }

    // ---- masked online softmax (log2 domain), P to wave-private LDS
#pragma unroll
    for (int qg = 0; qg < 2; ++qg) {
      float tmx = -1e30f;
#pragma unroll
      for (int t = 0; t < 4; ++t)
#pragma unroll
        for (int r = 0; r < 4; ++r) {
          float s = ((mbits[qg] >> (t * 4 + r)) & 1u) ? S[qg][t][r] : -1e30f;
          S[qg][t][r] = s;
          tmx = fmaxf(tmx, s);
        }
      tmx = fmaxf(tmx, __shfl_xor(tmx, 16));
      tmx = fmaxf(tmx, __shfl_xor(tmx, 32));
      const float mnew = fmaxf(mrow[qg], tmx);
      const float alpha = exp2f(mrow[qg] - mnew);
      float rs = 0.0f;
#pragma unroll
      for (int t = 0; t < 4; ++t) {
        bf16x4v pb;
#pragma unroll
        for (int r = 0; r < 4; ++r) {
          float p = exp2f(S[qg][t][r] - mnew);
          rs += p;
          pb[r] = (__bf16)p;
        }
        *(bf16x4v*)(Pw + (qg * 16 + l15) * PSTR + t * 16 + quad * 4) = pb;
      }
      rs += __shfl_xor(rs, 16);
      rs += __shfl_xor(rs, 32);
      lrow[qg] = lrow[qg] * alpha + rs;
      mrow[qg] = mnew;
      // rescale O (O rows are quad*4+r; alpha lives at lane l15 = q-row)
      float ar[4];
#pragma unroll
      for (int r = 0; r < 4; ++r) ar[r] = __shfl(alpha, (quad << 2) + r);
#pragma unroll
      for (int nt = 0; nt < 8; ++nt)
#pragma unroll
        for (int r = 0; r < 4; ++r) O[qg][nt][r] *= ar[r];
    }

    // ---- P: LDS -> A-layout fragments (wave-private, no barrier)
    bf16x8 pf[2][2];
#pragma unroll
    for (int qg = 0; qg < 2; ++qg)
#pragma unroll
      for (int js = 0; js < 2; ++js)
        pf[qg][js] =
            *(const bf16x8*)(Pw + (qg * 16 + l15) * PSTR + js * 32 + quad * 8);

    // ---- O += P V  (each vf read feeds 2 MFMAs)
#pragma unroll
    for (int nt = 0; nt < 8; ++nt) {
      const __bf16* vp = Vts + (nt * 16 + l15) * VSTR + quad * 8;
#pragma unroll
      for (int js = 0; js < 2; ++js) {
        bf16x8 vf = *(const bf16x8*)(vp + js * 32);
        O[0][nt] = __builtin_amdgcn_mfma_f32_16x16x32_bf16(pf[0][js], vf, O[0][nt], 0, 0, 0);
        O[1][nt] = __builtin_amdgcn_mfma_f32_16x16x32_bf16(pf[1][js], vf, O[1][nt], 0, 0, 0);
      }
    }

    __syncthreads();   // all waves done reading tile jt from LDS
    // ---- stage prefetched tile jn into LDS; compress its mask
#pragma unroll
    for (int p = 0; p < 4; ++p) {
      *(bf16x8*)(ksd + p * 16 * KSTR) = kr[p];
      *(bf16x8*)(vsd + p * 32 * VSTR) = vr[p];
    }
#pragma unroll
    for (int qg = 0; qg < 2; ++qg) {
      float mb = 0.f;
#pragma unroll
      for (int t = 0; t < 4; ++t)
#pragma unroll
        for (int r = 0; r < 4; ++r)
          mb = fmaf(mr[qg][t][r], (float)(1u << (t * 4 + r)), mb);
      mbits[qg] = (unsigned)mb;
    }
    __syncthreads();   // tile jn visible to all waves
  }

  // ---- epilogue: out[i][h] = O / l
#pragma unroll
  for (int qg = 0; qg < 2; ++qg) {
    const float inv = 1.0f / lrow[qg];
    float il[4];
#pragma unroll
    for (int r = 0; r < 4; ++r) il[r] = __shfl(inv, (quad << 2) + r);
    const long rowb = (long)b * NN + i0 + w * 32 + qg * 16 + quad * 4;
#pragma unroll
    for (int r = 0; r < 4; ++r) {
      float* op = out + (rowb + r) * HID;
#pragma unroll
      for (int nt = 0; nt < 8; ++nt) op[nt * 16 + l15] = O[qg][nt][r] * il[r];
    }
  }
}

// ---------------------------------------------------------------------------
extern "C" void kernel_launch(void* const* d_in, const int* in_sizes, int n_in,
                              void* d_out, int out_size, void* d_ws, size_t ws_size,
                              hipStream_t stream) {
  const float* x    = (const float*)d_in[0];
  const float* mask = (const float*)d_in[1];
  const float* Wv   = (const float*)d_in[2];
  const float* bv   = (const float*)d_in[3];
  const float* Wk   = (const float*)d_in[4];
  const float* bk   = (const float*)d_in[5];
  const float* Wq   = (const float*)d_in[6];
  const float* bq   = (const float*)d_in[7];
  float* out = (float*)d_out;

  __bf16* ws = (__bf16*)d_ws;
  __bf16* wt   = ws;                      // 3 * 128*128
  __bf16* qbf  = ws + 3 * DIN * HID;      // B*N*H
  __bf16* kbf  = qbf + (long)BB * NN * HID;
  __bf16* vtbf = kbf + (long)BB * NN * HID;

  wt_kernel<<<3, 256, 0, stream>>>(Wq, Wk, Wv, wt);
  proj_kernel<<<BB * NN / 64, 256, 0, stream>>>(x, wt, bq, bk, bv, qbf, kbf, vtbf);
  attn_kernel<<<512, 256, 0, stream>>>(qbf, kbf, vtbf, mask, out);
}